// Round 3
// baseline (176282.434 us; speedup 1.0000x reference)
//
#include <hip/hip_runtime.h>

typedef _Float16 half8 __attribute__((ext_vector_type(8)));
typedef _Float16 half4 __attribute__((ext_vector_type(4)));
typedef float f32x4 __attribute__((ext_vector_type(4)));

#define NSTEP 48
#define MT 16          // batch rows per workgroup (256 wgs cover 4096)
#define W0S 544        // W0 packed row stride: 256 x-feat | 256 h0 | 3 notes | 29 zero pad
#define W1S 512        // W1 packed row stride: 256 h0new | 256 h1
#define LDX 552        // lds_h0 row stride (fp16): [x 256 | h0 256 | sn 3 | zeros...]; 1104 B = 69*16 -> odd x16B, conflict-free b128
#define LDH1 264       // lds_h1 row stride; 528 B = 33*16 -> odd x16B

__device__ __forceinline__ float sigm(float x) { return 1.0f / (1.0f + __expf(-x)); }
__device__ __forceinline__ float tanh_f(float x) {
  float ax = fabsf(x);
  float e = __expf(-2.0f * ax);
  float t = (1.0f - e) / (1.0f + e);
  return copysignf(t, x);
}

// Pack weights (fp16):
//   W0h[n][0:256]   = W_ih0[n][0:256] (features)
//   W0h[n][256:512] = W_hh0[n]
//   W0h[n][512:515] = W_ih0[n][256:259] (shifted-note cols), [515:544) = 0
//   W1h[n][0:256]   = W_ih1[n],  W1h[n][256:512] = W_hh1[n]
//   b0 = b_ih0 + b_hh0, b1 = b_ih1 + b_hh1 (fp32)
__global__ void prep_weights(const float* __restrict__ Wih0, const float* __restrict__ Whh0,
                             const float* __restrict__ bih0, const float* __restrict__ bhh0,
                             const float* __restrict__ Wih1, const float* __restrict__ Whh1,
                             const float* __restrict__ bih1, const float* __restrict__ bhh1,
                             _Float16* __restrict__ W0h, _Float16* __restrict__ W1h,
                             float* __restrict__ b0, float* __restrict__ b1) {
  int n = blockIdx.x;      // 1024
  int k = threadIdx.x;     // 256
  W0h[n * W0S + k]       = (_Float16)Wih0[n * 259 + k];
  W0h[n * W0S + 256 + k] = (_Float16)Whh0[n * 256 + k];
  if (k < 32) W0h[n * W0S + 512 + k] = (k < 3) ? (_Float16)Wih0[n * 259 + 256 + k] : (_Float16)0.0f;
  W1h[n * W1S + k]       = (_Float16)Wih1[n * 256 + k];
  W1h[n * W1S + 256 + k] = (_Float16)Whh1[n * 256 + k];
  if (k == 0) { b0[n] = bih0[n] + bhh0[n]; b1[n] = bih1[n] + bhh1[n]; }
}

// 1024 threads = 16 waves; wave v owns units [v*16, v*16+16); all waves share batch rows [row0, row0+16).
// 1024-thread block forces <=128 VGPR/wave -> 4 waves/SIMD resident.
__global__ __launch_bounds__(1024, 4)
void noteaxis_main(const float* __restrict__ nf, const float* __restrict__ cond,
                   const _Float16* __restrict__ W0h, const _Float16* __restrict__ W1h,
                   const float* __restrict__ b0g, const float* __restrict__ b1g,
                   const float* __restrict__ Wout, const float* __restrict__ bout,
                   float* __restrict__ out) {
  __shared__ __align__(16) _Float16 lds_h0[MT][LDX];   // [x | h0 | sn | 0s]
  __shared__ __align__(16) _Float16 lds_h1[MT][LDH1];
  __shared__ float lds_b0[1024];
  __shared__ float lds_b1[1024];
  __shared__ float lds_part[16][MT][3];

  const int tid = threadIdx.x;
  const int v = tid >> 6;        // wave id 0..15; also = x-staging row
  const int lane = tid & 63;
  const int r = lane & 15;
  const int q = lane >> 4;
  const int row0 = blockIdx.x * MT;
  const int u0 = v * 16 + r;     // unit column for this lane

  for (int i = tid; i < MT * LDX; i += 1024) ((_Float16*)lds_h0)[i] = (_Float16)0.0f;
  for (int i = tid; i < MT * LDH1; i += 1024) ((_Float16*)lds_h1)[i] = (_Float16)0.0f;
  lds_b0[tid] = b0g[tid];
  lds_b1[tid] = b1g[tid];

  const _Float16* pB0 = W0h + (size_t)u0 * W0S + q * 8;
  const _Float16* pB1 = W1h + (size_t)u0 * W1S + q * 8;
  const float* pX = nf + ((size_t)(row0 + v) * NSTEP) * 256 + (lane << 2);  // this thread's x-staging source

  const float wo0 = Wout[0 * 256 + u0];
  const float wo1 = Wout[1 * 256 + u0];
  const float wo2 = Wout[2 * 256 + u0];
  const float bo0 = bout[0], bo1 = bout[1], bo2 = bout[2];

  float c0s[4], c1s[4];          // [g]; batch row m = q*4+g, unit u0
#pragma unroll
  for (int g = 0; g < 4; ++g) { c0s[g] = 0.0f; c1s[g] = 0.0f; }

  f32x4 acc[4];                  // [gate c], rows m = q*4+g, col u0
  half8 Bb[2][4];                // double-buffered B fragments (one kt each)

  auto loadB0 = [&](half8* d, int kt) {
#pragma unroll
    for (int c = 0; c < 4; ++c)
      d[c] = *(const half8*)(pB0 + (size_t)c * (256 * W0S) + kt * 32);
  };
  auto loadB1 = [&](half8* d, int kt) {
#pragma unroll
    for (int c = 0; c < 4; ++c)
      d[c] = *(const half8*)(pB1 + (size_t)c * (256 * W1S) + kt * 32);
  };
  auto mfma4 = [&](half8 a, half8* B) {
#pragma unroll
    for (int c = 0; c < 4; ++c)
      acc[c] = __builtin_amdgcn_mfma_f32_16x16x32_f16(a, B[c], acc[c], 0, 0, 0);
  };

  loadB0(Bb[0], 0);              // prologue: L0 kt0 for step 0 (in flight across init barrier)
  __syncthreads();

#pragma unroll 1
  for (int n = 0; n < NSTEP; ++n) {
    // ---- stage x (fp32->fp16) into lds_h0 cols [0,256) ----
    {
      const float4 xf = *(const float4*)(pX + (size_t)n * 256);
      half4 h4;
      h4[0] = (_Float16)xf.x; h4[1] = (_Float16)xf.y; h4[2] = (_Float16)xf.z; h4[3] = (_Float16)xf.w;
      *(half4*)&lds_h0[v][lane << 2] = h4;
    }
    // ---- stage shifted condition notes into cols [512,515) ----
    if (tid < MT) {
      float s0 = 0.f, s1 = 0.f, s2 = 0.f;
      if (n > 0) {
        const float* cp = cond + ((size_t)(row0 + tid) * NSTEP + (n - 1)) * 3;
        s0 = cp[0]; s1 = cp[1]; s2 = cp[2];
      }
      lds_h0[tid][512] = (_Float16)s0;
      lds_h0[tid][513] = (_Float16)s1;
      lds_h0[tid][514] = (_Float16)s2;
    }
    __syncthreads();  // B0

    // ---- Layer 0 GEMM: 17 kt over [x | h0 | sn+0s] ----
#pragma unroll
    for (int c = 0; c < 4; ++c) {
      float b = lds_b0[c * 256 + u0];
      f32x4 bz = {b, b, b, b};
      acc[c] = bz;
    }
#pragma unroll 1
    for (int kt = 0; kt < 17; ++kt) {
      half8 a = *(const half8*)&lds_h0[r][kt * 32 + q * 8];
      if (kt < 16) loadB0(Bb[(kt + 1) & 1], kt + 1);
      else         loadB1(Bb[1], 0);                    // prefetch L1 kt0 across barrier region
      mfma4(a, Bb[kt & 1]);
    }
    __syncthreads();  // B1: all waves done reading lds_h0 (x, h0(n-1), sn)

    // ---- cell 0: write h0(n) into lds_h0 cols [256,512) ----
#pragma unroll
    for (int g = 0; g < 4; ++g) {
      float i_ = acc[0][g], f_ = acc[1][g], g_ = acc[2][g], o_ = acc[3][g];
      float cc = sigm(f_) * c0s[g] + sigm(i_) * tanh_f(g_);
      c0s[g] = cc;
      lds_h0[q * 4 + g][256 + u0] = (_Float16)(sigm(o_) * tanh_f(cc));
    }
    __syncthreads();  // B2: h0(n) visible

    // ---- Layer 1 GEMM: kt 0..7 from h0(n), kt 8..15 from h1(n-1) ----
#pragma unroll
    for (int c = 0; c < 4; ++c) {
      float b = lds_b1[c * 256 + u0];
      f32x4 bz = {b, b, b, b};
      acc[c] = bz;
    }
#pragma unroll 1
    for (int kt = 0; kt < 16; ++kt) {
      half8 a = (kt < 8) ? *(const half8*)&lds_h0[r][256 + kt * 32 + q * 8]
                         : *(const half8*)&lds_h1[r][(kt - 8) * 32 + q * 8];
      if (kt < 15) loadB1(Bb[kt & 1], kt + 1);
      mfma4(a, Bb[(kt & 1) ^ 1]);
    }
    loadB0(Bb[0], 0);  // prefetch next step's L0 kt0 (after last mfma -> no WAR stall)
    __syncthreads();   // B3: all waves done reading lds_h0/lds_h1

    // ---- cell 1 + output-projection partials ----
    float part[4][3];
#pragma unroll
    for (int g = 0; g < 4; ++g) {
      float i_ = acc[0][g], f_ = acc[1][g], g_ = acc[2][g], o_ = acc[3][g];
      float cc = sigm(f_) * c1s[g] + sigm(i_) * tanh_f(g_);
      c1s[g] = cc;
      float hh = sigm(o_) * tanh_f(cc);
      lds_h1[q * 4 + g][u0] = (_Float16)hh;
      part[g][0] = hh * wo0;
      part[g][1] = hh * wo1;
      part[g][2] = hh * wo2;
    }
#pragma unroll
    for (int g = 0; g < 4; ++g)
#pragma unroll
      for (int ch = 0; ch < 3; ++ch) {
        float p = part[g][ch];
        p += __shfl_xor(p, 1);
        p += __shfl_xor(p, 2);
        p += __shfl_xor(p, 4);
        p += __shfl_xor(p, 8);
        part[g][ch] = p;
      }
    if (r == 0) {
#pragma unroll
      for (int g = 0; g < 4; ++g) {
        int m = q * 4 + g;
        lds_part[v][m][0] = part[g][0];
        lds_part[v][m][1] = part[g][1];
        lds_part[v][m][2] = part[g][2];
      }
    }
    __syncthreads();  // B4

    if (tid < MT * 3) {
      int m = tid / 3;
      int ch = tid - m * 3;
      float s = (ch == 0 ? bo0 : (ch == 1 ? bo1 : bo2));
#pragma unroll
      for (int w = 0; w < 16; ++w) s += lds_part[w][m][ch];
      if (ch < 2) s = 1.0f / (1.0f + __expf(-s));
      out[((size_t)(row0 + m) * NSTEP + n) * 3 + ch] = s;
    }
  }
}

extern "C" void kernel_launch(void* const* d_in, const int* in_sizes, int n_in,
                              void* d_out, int out_size, void* d_ws, size_t ws_size,
                              hipStream_t stream) {
  const float* nf   = (const float*)d_in[0];
  const float* cond = (const float*)d_in[1];
  const float* Wih0 = (const float*)d_in[2];
  const float* Whh0 = (const float*)d_in[3];
  const float* bih0 = (const float*)d_in[4];
  const float* bhh0 = (const float*)d_in[5];
  const float* Wih1 = (const float*)d_in[6];
  const float* Whh1 = (const float*)d_in[7];
  const float* bih1 = (const float*)d_in[8];
  const float* bhh1 = (const float*)d_in[9];
  const float* Wout = (const float*)d_in[10];
  const float* bout = (const float*)d_in[11];
  float* out = (float*)d_out;

  _Float16* W0h = (_Float16*)d_ws;                       // 1024*544*2 B
  _Float16* W1h = W0h + 1024 * W0S;                      // 1024*512*2 B
  float* b0 = (float*)(W1h + 1024 * W1S);                // 4 KB
  float* b1 = b0 + 1024;                                 // 4 KB

  prep_weights<<<1024, 256, 0, stream>>>(Wih0, Whh0, bih0, bhh0, Wih1, Whh1, bih1, bhh1, W0h, W1h, b0, b1);
  noteaxis_main<<<256, 1024, 0, stream>>>(nf, cond, W0h, W1h, b0, b1, Wout, bout, out);
}

// Round 4
// 5276.518 us; speedup vs baseline: 33.4089x; 33.4089x over previous
//
#include <hip/hip_runtime.h>

typedef _Float16 half8 __attribute__((ext_vector_type(8)));
typedef _Float16 half4 __attribute__((ext_vector_type(4)));
typedef float f32x4 __attribute__((ext_vector_type(4)));

#define NSTEP 48
#define MT 16          // batch rows per workgroup (256 wgs cover 4096)
#define W0S 544        // W0 packed row stride: 256 x-feat | 256 h0 | 3 notes | 29 zero pad
#define W1S 512        // W1 packed row stride: 256 h0new | 256 h1
#define LDX 552        // lds_h0 row stride (fp16): [x 256 | h0 256 | sn 3 | 0s]; 1104 B = 69*16 -> odd x16B
#define LDH1 264       // lds_h1 row stride; 528 B = 33*16 -> odd x16B

__device__ __forceinline__ float sigm(float x) { return 1.0f / (1.0f + __expf(-x)); }
__device__ __forceinline__ float tanh_f(float x) {
  float ax = fabsf(x);
  float e = __expf(-2.0f * ax);
  float t = (1.0f - e) / (1.0f + e);
  return copysignf(t, x);
}

__global__ void prep_weights(const float* __restrict__ Wih0, const float* __restrict__ Whh0,
                             const float* __restrict__ bih0, const float* __restrict__ bhh0,
                             const float* __restrict__ Wih1, const float* __restrict__ Whh1,
                             const float* __restrict__ bih1, const float* __restrict__ bhh1,
                             _Float16* __restrict__ W0h, _Float16* __restrict__ W1h,
                             float* __restrict__ b0, float* __restrict__ b1) {
  int n = blockIdx.x;      // 1024
  int k = threadIdx.x;     // 256
  W0h[n * W0S + k]       = (_Float16)Wih0[n * 259 + k];
  W0h[n * W0S + 256 + k] = (_Float16)Whh0[n * 256 + k];
  if (k < 32) W0h[n * W0S + 512 + k] = (k < 3) ? (_Float16)Wih0[n * 259 + 256 + k] : (_Float16)0.0f;
  W1h[n * W1S + k]       = (_Float16)Wih1[n * 256 + k];
  W1h[n * W1S + 256 + k] = (_Float16)Whh1[n * 256 + k];
  if (k == 0) { b0[n] = bih0[n] + bhh0[n]; b1[n] = bih1[n] + bhh1[n]; }
}

// 1024 threads = 16 waves; wave v owns units [v*16, v*16+16); all waves share batch rows [row0, row0+16).
__global__ __launch_bounds__(1024, 4)
void noteaxis_main(const float* __restrict__ nf, const float* __restrict__ cond,
                   const _Float16* __restrict__ W0h, const _Float16* __restrict__ W1h,
                   const float* __restrict__ b0g, const float* __restrict__ b1g,
                   const float* __restrict__ Wout, const float* __restrict__ bout,
                   float* __restrict__ out) {
  __shared__ __align__(16) _Float16 lds_h0[MT][LDX];   // [x | h0 | sn | 0s]
  __shared__ __align__(16) _Float16 lds_h1[MT][LDH1];
  __shared__ float lds_b0[1024];
  __shared__ float lds_b1[1024];
  __shared__ float lds_part[16][MT][3];

  const int tid = threadIdx.x;
  const int v = tid >> 6;
  const int lane = tid & 63;
  const int r = lane & 15;
  const int q = lane >> 4;
  const int row0 = blockIdx.x * MT;
  const int u0 = v * 16 + r;

  for (int i = tid; i < MT * LDX; i += 1024) ((_Float16*)lds_h0)[i] = (_Float16)0.0f;
  for (int i = tid; i < MT * LDH1; i += 1024) ((_Float16*)lds_h1)[i] = (_Float16)0.0f;
  lds_b0[tid] = b0g[tid];
  lds_b1[tid] = b1g[tid];

  const _Float16* pB0 = W0h + (size_t)u0 * W0S + q * 8;
  const _Float16* pB1 = W1h + (size_t)u0 * W1S + q * 8;
  const float* pX = nf + ((size_t)(row0 + v) * NSTEP) * 256 + (lane << 2);

  const float wo0 = Wout[0 * 256 + u0];
  const float wo1 = Wout[1 * 256 + u0];
  const float wo2 = Wout[2 * 256 + u0];
  const float bo0 = bout[0], bo1 = bout[1], bo2 = bout[2];

  float c0s[4], c1s[4];
#pragma unroll
  for (int g = 0; g < 4; ++g) { c0s[g] = 0.0f; c1s[g] = 0.0f; }

  f32x4 acc[4];
  half8 B0f[4], B1f[4];          // two named buffers -> lexically static indices only

  auto loadB0 = [&](half8 (&d)[4], int kt) {
#pragma unroll
    for (int c = 0; c < 4; ++c)
      d[c] = *(const half8*)(pB0 + (size_t)c * (256 * W0S) + kt * 32);
  };
  auto loadB1 = [&](half8 (&d)[4], int kt) {
#pragma unroll
    for (int c = 0; c < 4; ++c)
      d[c] = *(const half8*)(pB1 + (size_t)c * (256 * W1S) + kt * 32);
  };
  auto mfma4 = [&](half8 a, half8 (&B)[4]) {
#pragma unroll
    for (int c = 0; c < 4; ++c)
      acc[c] = __builtin_amdgcn_mfma_f32_16x16x32_f16(a, B[c], acc[c], 0, 0, 0);
  };
  auto ldsA0 = [&](int kt) -> half8 { return *(const half8*)&lds_h0[r][kt * 32 + q * 8]; };
  auto ldsA1 = [&](int kt) -> half8 {
    return (kt < 8) ? *(const half8*)&lds_h0[r][256 + kt * 32 + q * 8]
                    : *(const half8*)&lds_h1[r][(kt - 8) * 32 + q * 8];
  };

  loadB0(B0f, 0);                // prologue: L0 kt0 for step 0
  __syncthreads();

#pragma unroll 1
  for (int n = 0; n < NSTEP; ++n) {
    // ---- stage x (fp32->fp16) into lds_h0 cols [0,256) ----
    {
      const float4 xf = *(const float4*)(pX + (size_t)n * 256);
      half4 h4;
      h4[0] = (_Float16)xf.x; h4[1] = (_Float16)xf.y; h4[2] = (_Float16)xf.z; h4[3] = (_Float16)xf.w;
      *(half4*)&lds_h0[v][lane << 2] = h4;
    }
    if (tid < MT) {
      float s0 = 0.f, s1 = 0.f, s2 = 0.f;
      if (n > 0) {
        const float* cp = cond + ((size_t)(row0 + tid) * NSTEP + (n - 1)) * 3;
        s0 = cp[0]; s1 = cp[1]; s2 = cp[2];
      }
      lds_h0[tid][512] = (_Float16)s0;
      lds_h0[tid][513] = (_Float16)s1;
      lds_h0[tid][514] = (_Float16)s2;
    }
    __syncthreads();  // B0

    // ---- Layer 0 GEMM: 17 kt over [x | h0 | sn+0s], manual x2 double-buffer ----
#pragma unroll
    for (int c = 0; c < 4; ++c) {
      float b = lds_b0[c * 256 + u0];
      f32x4 bz = {b, b, b, b};
      acc[c] = bz;
    }
#pragma unroll
    for (int kt2 = 0; kt2 < 8; ++kt2) {
      half8 a0 = ldsA0(2 * kt2);
      loadB0(B1f, 2 * kt2 + 1);
      mfma4(a0, B0f);
      half8 a1 = ldsA0(2 * kt2 + 1);
      loadB0(B0f, (kt2 < 7) ? (2 * kt2 + 2) : 16);
      mfma4(a1, B1f);
    }
    {
      half8 a = ldsA0(16);       // sn extension tile
      loadB1(B1f, 0);            // prefetch L1 kt0 across the barrier region
      mfma4(a, B0f);
    }
    __syncthreads();  // B1: all waves done reading lds_h0 (x, h0(n-1), sn)

    // ---- cell 0: write h0(n) into lds_h0 cols [256,512) ----
#pragma unroll
    for (int g = 0; g < 4; ++g) {
      float i_ = acc[0][g], f_ = acc[1][g], g_ = acc[2][g], o_ = acc[3][g];
      float cc = sigm(f_) * c0s[g] + sigm(i_) * tanh_f(g_);
      c0s[g] = cc;
      lds_h0[q * 4 + g][256 + u0] = (_Float16)(sigm(o_) * tanh_f(cc));
    }
    __syncthreads();  // B2: h0(n) visible

    // ---- Layer 1 GEMM: 16 kt (h0new then h1), manual x2 double-buffer ----
#pragma unroll
    for (int c = 0; c < 4; ++c) {
      float b = lds_b1[c * 256 + u0];
      f32x4 bz = {b, b, b, b};
      acc[c] = bz;
    }
#pragma unroll
    for (int kt2 = 0; kt2 < 8; ++kt2) {
      half8 a0 = ldsA1(2 * kt2);
      loadB1(B0f, 2 * kt2 + 1);
      mfma4(a0, B1f);
      half8 a1 = ldsA1(2 * kt2 + 1);
      if (kt2 < 7) loadB1(B1f, 2 * kt2 + 2);
      mfma4(a1, B0f);
    }
    loadB0(B0f, 0);   // prefetch next step's L0 kt0
    __syncthreads();  // B3: all waves done reading lds_h0/lds_h1

    // ---- cell 1 + output-projection partials ----
    float part[4][3];
#pragma unroll
    for (int g = 0; g < 4; ++g) {
      float i_ = acc[0][g], f_ = acc[1][g], g_ = acc[2][g], o_ = acc[3][g];
      float cc = sigm(f_) * c1s[g] + sigm(i_) * tanh_f(g_);
      c1s[g] = cc;
      float hh = sigm(o_) * tanh_f(cc);
      lds_h1[q * 4 + g][u0] = (_Float16)hh;
      part[g][0] = hh * wo0;
      part[g][1] = hh * wo1;
      part[g][2] = hh * wo2;
    }
#pragma unroll
    for (int g = 0; g < 4; ++g)
#pragma unroll
      for (int ch = 0; ch < 3; ++ch) {
        float p = part[g][ch];
        p += __shfl_xor(p, 1);
        p += __shfl_xor(p, 2);
        p += __shfl_xor(p, 4);
        p += __shfl_xor(p, 8);
        part[g][ch] = p;
      }
    if (r == 0) {
#pragma unroll
      for (int g = 0; g < 4; ++g) {
        int m = q * 4 + g;
        lds_part[v][m][0] = part[g][0];
        lds_part[v][m][1] = part[g][1];
        lds_part[v][m][2] = part[g][2];
      }
    }
    __syncthreads();  // B4

    if (tid < MT * 3) {
      int m = tid / 3;
      int ch = tid - m * 3;
      float s = (ch == 0 ? bo0 : (ch == 1 ? bo1 : bo2));
#pragma unroll
      for (int w = 0; w < 16; ++w) s += lds_part[w][m][ch];
      if (ch < 2) s = 1.0f / (1.0f + __expf(-s));
      out[((size_t)(row0 + m) * NSTEP + n) * 3 + ch] = s;
    }
  }
}

extern "C" void kernel_launch(void* const* d_in, const int* in_sizes, int n_in,
                              void* d_out, int out_size, void* d_ws, size_t ws_size,
                              hipStream_t stream) {
  const float* nf   = (const float*)d_in[0];
  const float* cond = (const float*)d_in[1];
  const float* Wih0 = (const float*)d_in[2];
  const float* Whh0 = (const float*)d_in[3];
  const float* bih0 = (const float*)d_in[4];
  const float* bhh0 = (const float*)d_in[5];
  const float* Wih1 = (const float*)d_in[6];
  const float* Whh1 = (const float*)d_in[7];
  const float* bih1 = (const float*)d_in[8];
  const float* bhh1 = (const float*)d_in[9];
  const float* Wout = (const float*)d_in[10];
  const float* bout = (const float*)d_in[11];
  float* out = (float*)d_out;

  _Float16* W0h = (_Float16*)d_ws;                       // 1024*544*2 B
  _Float16* W1h = W0h + 1024 * W0S;                      // 1024*512*2 B
  float* b0 = (float*)(W1h + 1024 * W1S);                // 4 KB
  float* b1 = b0 + 1024;                                 // 4 KB

  prep_weights<<<1024, 256, 0, stream>>>(Wih0, Whh0, bih0, bhh0, Wih1, Whh1, bih1, bhh1, W0h, W1h, b0, b1);
  noteaxis_main<<<256, 1024, 0, stream>>>(nf, cond, W0h, W1h, b0, b1, Wout, bout, out);
}

// Round 5
// 5258.913 us; speedup vs baseline: 33.5207x; 1.0033x over previous
//
#include <hip/hip_runtime.h>

typedef _Float16 half8 __attribute__((ext_vector_type(8)));
typedef _Float16 half4 __attribute__((ext_vector_type(4)));
typedef float f32x4 __attribute__((ext_vector_type(4)));

#define NSTEP 48
#define MT 16          // batch rows per workgroup (256 wgs cover 4096)
#define W0S 544        // W0 packed row stride: 256 x-feat | 256 h0 | 3 notes | 29 zero pad
#define W1S 512        // W1 packed row stride: 256 h0new | 256 h1
#define LDX 552        // lds_h0 row stride (fp16): [x 256 | h0 256 | sn 3 | 0s]; 1104 B = 69*16 -> odd x16B
#define LDH1 264       // lds_h1 row stride; 528 B = 33*16 -> odd x16B

__device__ __forceinline__ float sigm(float x) { return 1.0f / (1.0f + __expf(-x)); }
__device__ __forceinline__ float tanh_f(float x) {
  float ax = fabsf(x);
  float e = __expf(-2.0f * ax);
  float t = (1.0f - e) / (1.0f + e);
  return copysignf(t, x);
}

__global__ void prep_weights(const float* __restrict__ Wih0, const float* __restrict__ Whh0,
                             const float* __restrict__ bih0, const float* __restrict__ bhh0,
                             const float* __restrict__ Wih1, const float* __restrict__ Whh1,
                             const float* __restrict__ bih1, const float* __restrict__ bhh1,
                             _Float16* __restrict__ W0h, _Float16* __restrict__ W1h,
                             float* __restrict__ b0, float* __restrict__ b1) {
  int n = blockIdx.x;      // 1024
  int k = threadIdx.x;     // 256
  W0h[n * W0S + k]       = (_Float16)Wih0[n * 259 + k];
  W0h[n * W0S + 256 + k] = (_Float16)Whh0[n * 256 + k];
  if (k < 32) W0h[n * W0S + 512 + k] = (k < 3) ? (_Float16)Wih0[n * 259 + 256 + k] : (_Float16)0.0f;
  W1h[n * W1S + k]       = (_Float16)Wih1[n * 256 + k];
  W1h[n * W1S + 256 + k] = (_Float16)Whh1[n * 256 + k];
  if (k == 0) { b0[n] = bih0[n] + bhh0[n]; b1[n] = bih1[n] + bhh1[n]; }
}

// 1024 threads = 16 waves; wave v owns units [v*16, v*16+16); all waves share batch rows [row0, row0+16).
// waves_per_eu(4,4): exactly 4 waves/EU resident -> 128-VGPR budget, forbids the 64-reg squeeze that spilled r3/r4.
__global__ __attribute__((amdgpu_flat_work_group_size(1024, 1024), amdgpu_waves_per_eu(4, 4)))
void noteaxis_main(const float* __restrict__ nf, const float* __restrict__ cond,
                   const _Float16* __restrict__ W0h, const _Float16* __restrict__ W1h,
                   const float* __restrict__ b0g, const float* __restrict__ b1g,
                   const float* __restrict__ Wout, const float* __restrict__ bout,
                   float* __restrict__ out) {
  __shared__ __align__(16) _Float16 lds_h0[MT][LDX];   // [x | h0 | sn | 0s]
  __shared__ __align__(16) _Float16 lds_h1[MT][LDH1];
  __shared__ float lds_b0[1024];
  __shared__ float lds_b1[1024];
  __shared__ float lds_part[16][MT][3];

  const int tid = threadIdx.x;
  const int v = tid >> 6;
  const int lane = tid & 63;
  const int r = lane & 15;
  const int q = lane >> 4;
  const int row0 = blockIdx.x * MT;
  const int u0 = v * 16 + r;

  for (int i = tid; i < MT * LDX; i += 1024) ((_Float16*)lds_h0)[i] = (_Float16)0.0f;
  for (int i = tid; i < MT * LDH1; i += 1024) ((_Float16*)lds_h1)[i] = (_Float16)0.0f;
  lds_b0[tid] = b0g[tid];
  lds_b1[tid] = b1g[tid];

  const _Float16* pB0 = W0h + (size_t)u0 * W0S + q * 8;
  const _Float16* pB1 = W1h + (size_t)u0 * W1S + q * 8;
  const float* pX = nf + ((size_t)(row0 + v) * NSTEP) * 256 + (lane << 2);

  const float wo0 = Wout[0 * 256 + u0];
  const float wo1 = Wout[1 * 256 + u0];
  const float wo2 = Wout[2 * 256 + u0];
  const float bo0 = bout[0], bo1 = bout[1], bo2 = bout[2];

  float c0s[4], c1s[4];
#pragma unroll
  for (int g = 0; g < 4; ++g) { c0s[g] = 0.0f; c1s[g] = 0.0f; }

  f32x4 acc[4];
  half8 P0[8], P1[8];            // pair-wide (2-kt) double buffers; indices always lexical constants

  // load kts {2*k2, 2*k2+1} of W0: d[c] = gate c of kt even, d[4+c] = gate c of kt odd
#define LOADB0_PAIR(D, K2)                                                              \
  {                                                                                     \
    _Pragma("unroll")                                                                   \
    for (int c = 0; c < 4; ++c) {                                                       \
      D[c]     = *(const half8*)(pB0 + (size_t)c * (256 * W0S) + (2 * (K2)) * 32);      \
      D[4 + c] = *(const half8*)(pB0 + (size_t)c * (256 * W0S) + (2 * (K2) + 1) * 32);  \
    }                                                                                   \
  }
#define LOADB0_TAIL(D)                                                                  \
  {                                                                                     \
    _Pragma("unroll")                                                                   \
    for (int c = 0; c < 4; ++c)                                                         \
      D[c] = *(const half8*)(pB0 + (size_t)c * (256 * W0S) + 16 * 32);                  \
  }
#define LOADB1_PAIR(D, K2)                                                              \
  {                                                                                     \
    _Pragma("unroll")                                                                   \
    for (int c = 0; c < 4; ++c) {                                                       \
      D[c]     = *(const half8*)(pB1 + (size_t)c * (256 * W1S) + (2 * (K2)) * 32);      \
      D[4 + c] = *(const half8*)(pB1 + (size_t)c * (256 * W1S) + (2 * (K2) + 1) * 32);  \
    }                                                                                   \
  }
#define MFMA4(A, B, OFF)                                                                \
  {                                                                                     \
    _Pragma("unroll")                                                                   \
    for (int c = 0; c < 4; ++c)                                                         \
      acc[c] = __builtin_amdgcn_mfma_f32_16x16x32_f16((A), (B)[(OFF) + c], acc[c], 0, 0, 0); \
  }
#define A0(KT) (*(const half8*)&lds_h0[r][(KT) * 32 + q * 8])
#define A1(KT) ((KT) < 8 ? *(const half8*)&lds_h0[r][256 + (KT) * 32 + q * 8]           \
                         : *(const half8*)&lds_h1[r][((KT) - 8) * 32 + q * 8])
#define L0_PAIR(CUR, NXT, P)                                                            \
  {                                                                                     \
    half8 a0 = A0(2 * (P));                                                             \
    half8 a1 = A0(2 * (P) + 1);                                                         \
    LOADB0_PAIR(NXT, (P) + 1);                                                          \
    MFMA4(a0, CUR, 0);                                                                  \
    MFMA4(a1, CUR, 4);                                                                  \
  }
#define L1_PAIR(CUR, NXT, P)                                                            \
  {                                                                                     \
    half8 a0 = A1(2 * (P));                                                             \
    half8 a1 = A1(2 * (P) + 1);                                                         \
    LOADB1_PAIR(NXT, (P) + 1);                                                          \
    MFMA4(a0, CUR, 0);                                                                  \
    MFMA4(a1, CUR, 4);                                                                  \
  }

  __syncthreads();

#pragma unroll 1
  for (int n = 0; n < NSTEP; ++n) {
    // ---- stage x (fp32->fp16) into lds_h0 cols [0,256) ----
    {
      const float4 xf = *(const float4*)(pX + (size_t)n * 256);
      half4 h4;
      h4[0] = (_Float16)xf.x; h4[1] = (_Float16)xf.y; h4[2] = (_Float16)xf.z; h4[3] = (_Float16)xf.w;
      *(half4*)&lds_h0[v][lane << 2] = h4;
    }
    if (tid < MT) {
      float s0 = 0.f, s1 = 0.f, s2 = 0.f;
      if (n > 0) {
        const float* cp = cond + ((size_t)(row0 + tid) * NSTEP + (n - 1)) * 3;
        s0 = cp[0]; s1 = cp[1]; s2 = cp[2];
      }
      lds_h0[tid][512] = (_Float16)s0;
      lds_h0[tid][513] = (_Float16)s1;
      lds_h0[tid][514] = (_Float16)s2;
    }
    __syncthreads();  // B0

    // ---- Layer 0 GEMM: 17 kts = 8 pairs + tail, depth-2 pipeline ----
#pragma unroll
    for (int c = 0; c < 4; ++c) {
      float b = lds_b0[c * 256 + u0];
      f32x4 bz = {b, b, b, b};
      acc[c] = bz;
    }
    LOADB0_PAIR(P0, 0);
    L0_PAIR(P0, P1, 0);
    L0_PAIR(P1, P0, 1);
    L0_PAIR(P0, P1, 2);
    L0_PAIR(P1, P0, 3);
    L0_PAIR(P0, P1, 4);
    L0_PAIR(P1, P0, 5);
    L0_PAIR(P0, P1, 6);
    {  // pair 7 (data in P1), next = tail kt16 -> P0
      half8 a0 = A0(14);
      half8 a1 = A0(15);
      LOADB0_TAIL(P0);
      MFMA4(a0, P1, 0);
      MFMA4(a1, P1, 4);
    }
    {  // tail kt16 (sn extension)
      half8 a = A0(16);
      MFMA4(a, P0, 0);
    }
    __syncthreads();  // B1: all waves done reading lds_h0 (x, h0(n-1), sn)

    // ---- cell 0: write h0(n) into lds_h0 cols [256,512) ----
#pragma unroll
    for (int g = 0; g < 4; ++g) {
      float i_ = acc[0][g], f_ = acc[1][g], g_ = acc[2][g], o_ = acc[3][g];
      float cc = sigm(f_) * c0s[g] + sigm(i_) * tanh_f(g_);
      c0s[g] = cc;
      lds_h0[q * 4 + g][256 + u0] = (_Float16)(sigm(o_) * tanh_f(cc));
    }
    __syncthreads();  // B2: h0(n) visible

    // ---- Layer 1 GEMM: 16 kts = 8 pairs, depth-2 pipeline ----
#pragma unroll
    for (int c = 0; c < 4; ++c) {
      float b = lds_b1[c * 256 + u0];
      f32x4 bz = {b, b, b, b};
      acc[c] = bz;
    }
    LOADB1_PAIR(P0, 0);
    L1_PAIR(P0, P1, 0);
    L1_PAIR(P1, P0, 1);
    L1_PAIR(P0, P1, 2);
    L1_PAIR(P1, P0, 3);
    L1_PAIR(P0, P1, 4);
    L1_PAIR(P1, P0, 5);
    L1_PAIR(P0, P1, 6);
    {  // pair 7 (data in P1), no next load
      half8 a0 = A1(14);
      half8 a1 = A1(15);
      MFMA4(a0, P1, 0);
      MFMA4(a1, P1, 4);
    }
    __syncthreads();  // B3: all waves done reading lds_h0/lds_h1

    // ---- cell 1 + output-projection partials ----
    float part[4][3];
#pragma unroll
    for (int g = 0; g < 4; ++g) {
      float i_ = acc[0][g], f_ = acc[1][g], g_ = acc[2][g], o_ = acc[3][g];
      float cc = sigm(f_) * c1s[g] + sigm(i_) * tanh_f(g_);
      c1s[g] = cc;
      float hh = sigm(o_) * tanh_f(cc);
      lds_h1[q * 4 + g][u0] = (_Float16)hh;
      part[g][0] = hh * wo0;
      part[g][1] = hh * wo1;
      part[g][2] = hh * wo2;
    }
#pragma unroll
    for (int g = 0; g < 4; ++g)
#pragma unroll
      for (int ch = 0; ch < 3; ++ch) {
        float p = part[g][ch];
        p += __shfl_xor(p, 1);
        p += __shfl_xor(p, 2);
        p += __shfl_xor(p, 4);
        p += __shfl_xor(p, 8);
        part[g][ch] = p;
      }
    if (r == 0) {
#pragma unroll
      for (int g = 0; g < 4; ++g) {
        int m = q * 4 + g;
        lds_part[v][m][0] = part[g][0];
        lds_part[v][m][1] = part[g][1];
        lds_part[v][m][2] = part[g][2];
      }
    }
    __syncthreads();  // B4

    if (tid < MT * 3) {
      int m = tid / 3;
      int ch = tid - m * 3;
      float s = (ch == 0 ? bo0 : (ch == 1 ? bo1 : bo2));
#pragma unroll
      for (int w = 0; w < 16; ++w) s += lds_part[w][m][ch];
      if (ch < 2) s = 1.0f / (1.0f + __expf(-s));
      out[((size_t)(row0 + m) * NSTEP + n) * 3 + ch] = s;
    }
  }
}

extern "C" void kernel_launch(void* const* d_in, const int* in_sizes, int n_in,
                              void* d_out, int out_size, void* d_ws, size_t ws_size,
                              hipStream_t stream) {
  const float* nf   = (const float*)d_in[0];
  const float* cond = (const float*)d_in[1];
  const float* Wih0 = (const float*)d_in[2];
  const float* Whh0 = (const float*)d_in[3];
  const float* bih0 = (const float*)d_in[4];
  const float* bhh0 = (const float*)d_in[5];
  const float* Wih1 = (const float*)d_in[6];
  const float* Whh1 = (const float*)d_in[7];
  const float* bih1 = (const float*)d_in[8];
  const float* bhh1 = (const float*)d_in[9];
  const float* Wout = (const float*)d_in[10];
  const float* bout = (const float*)d_in[11];
  float* out = (float*)d_out;

  _Float16* W0h = (_Float16*)d_ws;                       // 1024*544*2 B
  _Float16* W1h = W0h + 1024 * W0S;                      // 1024*512*2 B
  float* b0 = (float*)(W1h + 1024 * W1S);                // 4 KB
  float* b1 = b0 + 1024;                                 // 4 KB

  prep_weights<<<1024, 256, 0, stream>>>(Wih0, Whh0, bih0, bhh0, Wih1, Whh1, bih1, bhh1, W0h, W1h, b0, b1);
  noteaxis_main<<<256, 1024, 0, stream>>>(nf, cond, W0h, W1h, b0, b1, Wout, bout, out);
}